// Round 5
// baseline (151.443 us; speedup 1.0000x reference)
//
#include <hip/hip_runtime.h>

// AliasFreeActivation fused kernel, v5: ONE plane per block, scalar f32.
// v4 post-mortem: float2 ops were scalarized by the compiler (VALU-inst count
// matches 2x scalar; VGPR=68 fits), so plane-pairing bought nothing while its
// 48.6 KB LDS capped occupancy at 3 blocks/CU (44% issue-idle). v5 keeps the
// proven v4 skeleton (named-reg rolling windows, LDS overlay) but single-plane:
// LDS = 114*53*4 = 24168 B -> 6 blocks/CU = 24 waves/CU (2x).
//
// Math (identical to v1..v4, all passed correctness):
//   upH -> (upW + leaky + downW fused) -> downH, crop folded in.
//   hi[l] = sum_{t=0..5} x[m0+t]*up[c0-4t], m0=(l+5)>>2, c0=20+((l+1)&3)
//   out[o] = sum_k hl[2o+k]*dn[11-k]

#define VFMA(A, S, C) fmaf((A), (S), (C))

// ---- pass 2: one upsampled sample j from 6 named taps, leaky, scatter ----
#define SCATTER(J, hv)                                                        \
    _Pragma("unroll")                                                         \
    for (int k = (J) & 1; k <= 11; k += 2) {                                  \
        if ((J) - k >= 0 && (((J) - k) >> 1) < 26)                            \
            acc[((J) - k) >> 1] = VFMA(hv, dn[11 - k], acc[((J) - k) >> 1]);  \
    }

#define DO_J(J, A, B, C, D, E, F)                                             \
    do {                                                                      \
        const int q_ = ((J) + 1) & 3;                                         \
        float h_ = (A) * up[20 + q_];                                         \
        h_ = VFMA((B), up[16 + q_], h_);                                      \
        h_ = VFMA((C), up[12 + q_], h_);                                      \
        h_ = VFMA((D), up[8 + q_], h_);                                       \
        h_ = VFMA((E), up[4 + q_], h_);                                       \
        h_ = VFMA((F), up[q_], h_);                                           \
        h_ = fmaxf(h_, 0.2f * h_);                                            \
        SCATTER(J, h_);                                                       \
    } while (0)

// Entering GROUP(G): regs hold taps G-1..G+4 in (T0..T5). Load tap G+5 into
// T0 (tap G-1 is dead) -> taps G..G+5 in (T1..T5,T0); emit 4 samples.
#define GROUP(G, T0, T1, T2, T3, T4, T5)                                      \
    do {                                                                      \
        T0 = wbase[(G) + 5];                                                  \
        DO_J(4 * (G) - 1, T1, T2, T3, T4, T5, T0);                            \
        DO_J(4 * (G), T1, T2, T3, T4, T5, T0);                                \
        DO_J(4 * (G) + 1, T1, T2, T3, T4, T5, T0);                            \
        DO_J(4 * (G) + 2, T1, T2, T3, T4, T5, T0);                            \
    } while (0)

#define GROUP_TAIL(T0, T1, T2, T3, T4, T5)                                    \
    do {                                                                      \
        T0 = wbase[20];                                                       \
        DO_J(59, T1, T2, T3, T4, T5, T0);                                     \
        DO_J(60, T1, T2, T3, T4, T5, T0);                                     \
        DO_J(61, T1, T2, T3, T4, T5, T0);                                     \
    } while (0)

// ---- pass 3: output row J from 12 named row-regs (rows 2J..2J+11) ----
#define P3LD(RA, RB, M)                                                       \
    RA = p3b[(M)*53];                                                         \
    RB = p3b[((M) + 1) * 53];

#define P3OUT(J, A, B, C, D, E, F, G, H, I, JJ, K, L)                         \
    do {                                                                      \
        float a_ = (A) * dn[11];                                              \
        a_ = VFMA((B), dn[10], a_);                                           \
        a_ = VFMA((C), dn[9], a_);                                            \
        a_ = VFMA((D), dn[8], a_);                                            \
        a_ = VFMA((E), dn[7], a_);                                            \
        a_ = VFMA((F), dn[6], a_);                                            \
        a_ = VFMA((G), dn[5], a_);                                            \
        a_ = VFMA((H), dn[4], a_);                                            \
        a_ = VFMA((I), dn[3], a_);                                            \
        a_ = VFMA((JJ), dn[2], a_);                                           \
        a_ = VFMA((K), dn[1], a_);                                            \
        a_ = VFMA((L), dn[0], a_);                                            \
        op0[(13 * s + (J)) * 52 + ow] = a_;                                   \
    } while (0)

__global__ __launch_bounds__(256, 6)
void afa_kernel(const float* __restrict__ x,
                const float* __restrict__ upf,
                const float* __restrict__ dnf,
                float* __restrict__ out)
{
    // Overlay: tH rows stride 35 (first 3990 floats), later t2 rows stride 53.
    __shared__ float buf[114 * 53];   // 24168 bytes -> 6 blocks/CU

    const int tid = threadIdx.x;
    const size_t q0 = (size_t)blockIdx.x;
    const float* __restrict__ xp0 = x + q0 * 1296;
    float* __restrict__ op0 = out + q0 * 2704;

    // filters -> uniform registers (scalar loads; constant indices)
    float up[24];
#pragma unroll
    for (int i = 0; i < 24; ++i) up[i] = upf[i];
    float dn[12];
#pragma unroll
    for (int i = 0; i < 12; ++i) dn[i] = dnf[i];

    // ---------------- Pass 1: upsample along H ----------------
    if (tid < 204) {
        const int s1 = tid / 34;
        const int mw = tid % 34 + 1;

        float xr[11];                       // x rows 5s+1 .. 5s+11 (clamped)
#pragma unroll
        for (int jj = 0; jj < 11; ++jj) {
            int row = 5 * s1 + 1 + jj;
            row = row > 35 ? 35 : row;      // clamp; clamped values never used
            xr[jj] = xp0[row * 36 + mw];
        }
        const int lh0  = 20 * s1;
        const int jmax = (s1 == 5) ? 14 : 20;
#pragma unroll
        for (int j = 0; j < 20; ++j) {
            if (j < jmax) {
                const int rel = ((j + 5) >> 2) - 1;   // compile-time
                const int c0  = 20 + ((j + 1) & 3);   // compile-time
                float a = 0.f;
#pragma unroll
                for (int t = 0; t < 6; ++t)
                    a = VFMA(xr[rel + t], up[c0 - 4 * t], a);
                buf[(lh0 + j) * 35 + (mw - 1)] = a;   // tH region
            }
        }
    }
    __syncthreads();

    // ---------- Pass 2: upW + leaky + downW, named-reg rolling window ----------
    const int  lh   = tid % 114;
    const int  p    = tid / 114;            // 0/1 for tid<228
    const bool act2 = tid < 228;
    float acc[26];                          // static-index only -> registers
    if (act2) {
        const float* __restrict__ wbase = &buf[lh * 35 + 13 * p];
        float w0 = wbase[0], w1 = wbase[1], w2 = wbase[2],
              w3 = wbase[3], w4 = wbase[4], w5 = wbase[5];
#pragma unroll
        for (int o = 0; o < 26; ++o) acc[o] = 0.f;

        DO_J(0, w0, w1, w2, w3, w4, w5);    // rel=0: taps 0..5
        DO_J(1, w0, w1, w2, w3, w4, w5);
        DO_J(2, w0, w1, w2, w3, w4, w5);
        GROUP(1,  w0, w1, w2, w3, w4, w5);  // -> taps 1..6 in (w1..w5,w0)
        GROUP(2,  w1, w2, w3, w4, w5, w0);
        GROUP(3,  w2, w3, w4, w5, w0, w1);
        GROUP(4,  w3, w4, w5, w0, w1, w2);
        GROUP(5,  w4, w5, w0, w1, w2, w3);
        GROUP(6,  w5, w0, w1, w2, w3, w4);
        GROUP(7,  w0, w1, w2, w3, w4, w5);
        GROUP(8,  w1, w2, w3, w4, w5, w0);
        GROUP(9,  w2, w3, w4, w5, w0, w1);
        GROUP(10, w3, w4, w5, w0, w1, w2);
        GROUP(11, w4, w5, w0, w1, w2, w3);
        GROUP(12, w5, w0, w1, w2, w3, w4);
        GROUP(13, w0, w1, w2, w3, w4, w5);
        GROUP(14, w1, w2, w3, w4, w5, w0);
        GROUP_TAIL(w2, w3, w4, w5, w0, w1); // tap 20; j=59..61
    }
    __syncthreads();   // all tH reads complete before any t2 write (overlay)

    if (act2) {
        float* __restrict__ tw = &buf[lh * 53 + 26 * p];
#pragma unroll
        for (int o = 0; o < 26; ++o) tw[o] = acc[o];  // t2 region
    }
    __syncthreads();

    // ---------------- Pass 3: downsample along H + store ----------------
    if (tid < 208) {
        const int ow = tid % 52;
        const int s  = tid / 52;
        const float* __restrict__ p3b = &buf[(26 * s) * 53 + ow];

        float r0, r1, r2, r3, r4, r5, r6, r7, r8, r9, r10, r11;
        P3LD(r0, r1, 0)  P3LD(r2, r3, 2)  P3LD(r4, r5, 4)
        P3LD(r6, r7, 6)  P3LD(r8, r9, 8)  P3LD(r10, r11, 10)

        P3OUT(0, r0, r1, r2, r3, r4, r5, r6, r7, r8, r9, r10, r11);
        P3LD(r0, r1, 12)
        P3OUT(1, r2, r3, r4, r5, r6, r7, r8, r9, r10, r11, r0, r1);
        P3LD(r2, r3, 14)
        P3OUT(2, r4, r5, r6, r7, r8, r9, r10, r11, r0, r1, r2, r3);
        P3LD(r4, r5, 16)
        P3OUT(3, r6, r7, r8, r9, r10, r11, r0, r1, r2, r3, r4, r5);
        P3LD(r6, r7, 18)
        P3OUT(4, r8, r9, r10, r11, r0, r1, r2, r3, r4, r5, r6, r7);
        P3LD(r8, r9, 20)
        P3OUT(5, r10, r11, r0, r1, r2, r3, r4, r5, r6, r7, r8, r9);
        P3LD(r10, r11, 22)
        P3OUT(6, r0, r1, r2, r3, r4, r5, r6, r7, r8, r9, r10, r11);
        P3LD(r0, r1, 24)
        P3OUT(7, r2, r3, r4, r5, r6, r7, r8, r9, r10, r11, r0, r1);
        P3LD(r2, r3, 26)
        P3OUT(8, r4, r5, r6, r7, r8, r9, r10, r11, r0, r1, r2, r3);
        P3LD(r4, r5, 28)
        P3OUT(9, r6, r7, r8, r9, r10, r11, r0, r1, r2, r3, r4, r5);
        P3LD(r6, r7, 30)
        P3OUT(10, r8, r9, r10, r11, r0, r1, r2, r3, r4, r5, r6, r7);
        P3LD(r8, r9, 32)
        P3OUT(11, r10, r11, r0, r1, r2, r3, r4, r5, r6, r7, r8, r9);
        P3LD(r10, r11, 34)
        P3OUT(12, r0, r1, r2, r3, r4, r5, r6, r7, r8, r9, r10, r11);
    }
}

extern "C" void kernel_launch(void* const* d_in, const int* in_sizes, int n_in,
                              void* d_out, int out_size, void* d_ws, size_t ws_size,
                              hipStream_t stream)
{
    const float* x  = (const float*)d_in[0];   // (16,512,36,36)
    const float* up = (const float*)d_in[1];   // (24,)
    const float* dn = (const float*)d_in[2];   // (12,)
    float* out = (float*)d_out;                // (16,512,52,52)

    afa_kernel<<<dim3(16 * 512), dim3(256), 0, stream>>>(x, up, dn, out);
}